// Round 1
// baseline (1180.957 us; speedup 1.0000x reference)
//
#include <hip/hip_runtime.h>
#include <hip/hip_bf16.h>

#define B_    2
#define H_    16
#define L_    2048
#define D_    64
#define QT    64              // q rows per block
#define KTILE 64              // k cols per iteration
#define NKT   (L_ / KTILE)    // 32
#define PITCH 72              // bf16 elems per row: 144B rows, 16B-aligned, conflict-friendly
#define VPITCH 70             // Vbuf pitch (u16 ops only): makes column reads conflict-free
#define MPITCH 132            // mask row pitch (u16): breaks 256B power-of-2 stride

typedef __bf16 bf16x8 __attribute__((ext_vector_type(8)));
typedef float  f32x4  __attribute__((ext_vector_type(4)));

__device__ __forceinline__ f32x4 mfma16(bf16x8 a, bf16x8 b, f32x4 c) {
    return __builtin_amdgcn_mfma_f32_16x16x32_bf16(a, b, c, 0, 0, 0);
}

__global__ __launch_bounds__(256)
void attn_fused(const float* __restrict__ Qg, const float* __restrict__ Kg,
                const float* __restrict__ Vg, const int* __restrict__ validg,
                const float* __restrict__ scaleg,
                float* __restrict__ outR, float* __restrict__ outW)
{
    // K tile split into hi/lo bf16 for near-fp32 QK^T precision
    __shared__ __attribute__((aligned(16))) __bf16 KbufH[KTILE][PITCH];
    __shared__ __attribute__((aligned(16))) __bf16 KbufL[KTILE][PITCH];
    __shared__ __attribute__((aligned(16))) __bf16 Vbuf[KTILE][VPITCH];  // [kk][d]
    __shared__ __attribute__((aligned(16))) __bf16 Pbuf[QT][PITCH];      // [q][kk]
    __shared__ unsigned short Mask[QT][MPITCH];  // bit (kk&15) of word [q][kk>>4]

    const int tid  = threadIdx.x;
    const int wv   = tid >> 6;        // wave 0..3
    const int lane = tid & 63;
    const int ln   = lane & 15;       // n / col index in fragments
    const int qd   = lane >> 4;       // quad 0..3

    // XCD-grouping swizzle: blocks on one XCD (idx%8) share a small set of bh
    const int bidx = blockIdx.x;
    const int bh   = (bidx & 7) * 4 + ((bidx >> 3) & 3);  // 0..31
    const int qt   = bidx >> 5;                            // 0..31

    const float scale = scaleg[0];

    const float* Qb = Qg + ((size_t)bh * L_ + (size_t)qt * QT) * D_;
    const float* Kb = Kg + (size_t)bh * L_ * D_;
    const float* Vb = Vg + (size_t)bh * L_ * D_;
    const int*   Mb = validg + ((size_t)bh * L_ + (size_t)qt * QT) * (size_t)L_;
    float* Ob = outR + ((size_t)bh * L_ + (size_t)qt * QT) * D_;
    float* Wb = outW + ((size_t)bh * L_ + (size_t)qt * QT) * (size_t)L_;

    // ---- persistent A fragments: Q rows (hi/lo split) ----
    // A[m=lane&15][k=quad*8+j]; frag f covers d = f*32 .. f*32+31
    bf16x8 aH[2], aL[2];
    {
        const float* qrow = Qb + (size_t)(wv * 16 + ln) * D_;
#pragma unroll
        for (int f = 0; f < 2; ++f) {
            f32x4 x0 = *(const f32x4*)(qrow + f * 32 + qd * 8);
            f32x4 x1 = *(const f32x4*)(qrow + f * 32 + qd * 8 + 4);
            bf16x8 h, l;
#pragma unroll
            for (int j = 0; j < 4; ++j) {
                float v0 = x0[j], v1 = x1[j];
                __bf16 h0 = (__bf16)v0, h1 = (__bf16)v1;
                h[j] = h0; h[4 + j] = h1;
                l[j]     = (__bf16)(v0 - (float)h0);
                l[4 + j] = (__bf16)(v1 - (float)h1);
            }
            aH[f] = h; aL[f] = l;
        }
    }

    const int sr = tid >> 2;          // staging row 0..63
    const int sc = (tid & 3) * 16;    // staging col chunk

    auto stageK = [&](int kt) {
        const float* src = Kb + (size_t)(kt * KTILE + sr) * D_ + sc;
        f32x4 w0 = *(const f32x4*)(src);
        f32x4 w1 = *(const f32x4*)(src + 4);
        f32x4 w2 = *(const f32x4*)(src + 8);
        f32x4 w3 = *(const f32x4*)(src + 12);
        bf16x8 h0, h1, l0, l1;
#pragma unroll
        for (int j = 0; j < 4; ++j) {
            { float v = w0[j]; __bf16 h = (__bf16)v; h0[j]   = h; l0[j]   = (__bf16)(v - (float)h); }
            { float v = w1[j]; __bf16 h = (__bf16)v; h0[4+j] = h; l0[4+j] = (__bf16)(v - (float)h); }
            { float v = w2[j]; __bf16 h = (__bf16)v; h1[j]   = h; l1[j]   = (__bf16)(v - (float)h); }
            { float v = w3[j]; __bf16 h = (__bf16)v; h1[4+j] = h; l1[4+j] = (__bf16)(v - (float)h); }
        }
        *(bf16x8*)&KbufH[sr][sc]     = h0;
        *(bf16x8*)&KbufH[sr][sc + 8] = h1;
        *(bf16x8*)&KbufL[sr][sc]     = l0;
        *(bf16x8*)&KbufL[sr][sc + 8] = l1;
    };

    // ================= PHASE 1: row sums (and mask packing) =================
    float lsum[4] = {0.f, 0.f, 0.f, 0.f};

    for (int kt = 0; kt < NKT; ++kt) {
        __syncthreads();                 // protect LDS from previous iteration's readers
        stageK(kt);
        {   // read valid once from HBM, pack to bits in LDS (persists whole kernel)
            const int* src = Mb + (size_t)sr * L_ + kt * KTILE + sc;
            int vals[16];
            *(int4*)(vals)      = *(const int4*)(src);
            *(int4*)(vals + 4)  = *(const int4*)(src + 4);
            *(int4*)(vals + 8)  = *(const int4*)(src + 8);
            *(int4*)(vals + 12) = *(const int4*)(src + 12);
            unsigned m = 0;
#pragma unroll
            for (int i = 0; i < 16; ++i) m |= (unsigned)(vals[i] > 0) << i;
            Mask[sr][kt * 4 + (tid & 3)] = (unsigned short)m;
        }
        __syncthreads();
#pragma unroll
        for (int ct = 0; ct < 4; ++ct) {
            const int kr = ct * 16 + ln;
            bf16x8 bh0 = *(const bf16x8*)&KbufH[kr][qd * 8];
            bf16x8 bh1 = *(const bf16x8*)&KbufH[kr][32 + qd * 8];
            bf16x8 bl0 = *(const bf16x8*)&KbufL[kr][qd * 8];
            bf16x8 bl1 = *(const bf16x8*)&KbufL[kr][32 + qd * 8];
            f32x4 acc = {0.f, 0.f, 0.f, 0.f};
            acc = mfma16(aL[0], bh0, acc);
            acc = mfma16(aL[1], bh1, acc);
            acc = mfma16(aH[0], bl0, acc);
            acc = mfma16(aH[1], bl1, acc);
            acc = mfma16(aH[0], bh0, acc);
            acc = mfma16(aH[1], bh1, acc);
#pragma unroll
            for (int r = 0; r < 4; ++r) {
                unsigned mb = Mask[wv * 16 + qd * 4 + r][kt * 4 + ct];
                float bit = (float)((mb >> ln) & 1u);
                lsum[r] += bit * __expf(acc[r] * scale);
            }
        }
    }

    // reduce row sums across the 16-lane groups (cols); result broadcast to all lanes
    float invl[4];
#pragma unroll
    for (int r = 0; r < 4; ++r) {
        float v = lsum[r];
        v += __shfl_xor(v, 1);
        v += __shfl_xor(v, 2);
        v += __shfl_xor(v, 4);
        v += __shfl_xor(v, 8);
        invl[r] = v > 0.f ? 1.f / v : 0.f;   // fully-masked row -> all zeros (matches NaN->0)
    }

    // ================= PHASE 2: recompute S, write att_w, accumulate O =================
    f32x4 accO[4];
#pragma unroll
    for (int i = 0; i < 4; ++i) accO[i] = (f32x4){0.f, 0.f, 0.f, 0.f};

    for (int kt = 0; kt < NKT; ++kt) {
        __syncthreads();
        stageK(kt);
        {   // stage V tile row-major [kk][d], pitch 70 (odd dword stride => conflict-free col reads)
            const float* src = Vb + (size_t)(kt * KTILE + sr) * D_ + sc;
            float tv[16];
            *(f32x4*)(tv)      = *(const f32x4*)(src);
            *(f32x4*)(tv + 4)  = *(const f32x4*)(src + 4);
            *(f32x4*)(tv + 8)  = *(const f32x4*)(src + 8);
            *(f32x4*)(tv + 12) = *(const f32x4*)(src + 12);
#pragma unroll
            for (int i = 0; i < 8; ++i) {
                __bf16 b0 = (__bf16)tv[2 * i], b1 = (__bf16)tv[2 * i + 1];
                unsigned packed = ((unsigned)*(unsigned short*)&b1 << 16) | *(unsigned short*)&b0;
                *(unsigned*)&Vbuf[sr][sc + 2 * i] = packed;
            }
        }
        __syncthreads();
#pragma unroll
        for (int ct = 0; ct < 4; ++ct) {
            const int kr = ct * 16 + ln;
            bf16x8 bh0 = *(const bf16x8*)&KbufH[kr][qd * 8];
            bf16x8 bh1 = *(const bf16x8*)&KbufH[kr][32 + qd * 8];
            bf16x8 bl0 = *(const bf16x8*)&KbufL[kr][qd * 8];
            bf16x8 bl1 = *(const bf16x8*)&KbufL[kr][32 + qd * 8];
            f32x4 acc = {0.f, 0.f, 0.f, 0.f};
            acc = mfma16(aL[0], bh0, acc);
            acc = mfma16(aL[1], bh1, acc);
            acc = mfma16(aH[0], bl0, acc);
            acc = mfma16(aH[1], bl1, acc);
            acc = mfma16(aH[0], bh0, acc);
            acc = mfma16(aH[1], bh1, acc);
#pragma unroll
            for (int r = 0; r < 4; ++r) {
                const int qrow = wv * 16 + qd * 4 + r;
                unsigned mb = Mask[qrow][kt * 4 + ct];
                float bit = (float)((mb >> ln) & 1u);
                float p = bit * __expf(acc[r] * scale) * invl[r];
                Wb[(size_t)qrow * L_ + (size_t)(kt * KTILE + ct * 16 + ln)] = p;
                Pbuf[qrow][ct * 16 + ln] = (__bf16)p;   // own-wave rows only: no barrier needed
            }
        }
        // ---- PV: O[q][d] += P[q][kk] * V[kk][d] ----
        bf16x8 p0 = *(const bf16x8*)&Pbuf[wv * 16 + ln][qd * 8];
        bf16x8 p1 = *(const bf16x8*)&Pbuf[wv * 16 + ln][32 + qd * 8];
#pragma unroll
        for (int c2 = 0; c2 < 4; ++c2) {
            bf16x8 v0, v1;
#pragma unroll
            for (int j = 0; j < 8; ++j) {
                v0[j] = Vbuf[qd * 8 + j][c2 * 16 + ln];       // B[k=kk][n=d]
                v1[j] = Vbuf[32 + qd * 8 + j][c2 * 16 + ln];
            }
            accO[c2] = mfma16(p0, v0, accO[c2]);
            accO[c2] = mfma16(p1, v1, accO[c2]);
        }
    }

    // ---- write result ----
#pragma unroll
    for (int c2 = 0; c2 < 4; ++c2)
#pragma unroll
        for (int r = 0; r < 4; ++r)
            Ob[(size_t)(wv * 16 + qd * 4 + r) * D_ + (c2 * 16 + ln)] = accO[c2][r];
}

extern "C" void kernel_launch(void* const* d_in, const int* in_sizes, int n_in,
                              void* d_out, int out_size, void* d_ws, size_t ws_size,
                              hipStream_t stream) {
    const float* q     = (const float*)d_in[0];
    const float* k     = (const float*)d_in[1];
    const float* v     = (const float*)d_in[2];
    const int*   valid = (const int*)d_in[3];
    const float* scale = (const float*)d_in[4];

    float* out_res  = (float*)d_out;
    float* out_attw = out_res + (size_t)B_ * H_ * L_ * D_;

    dim3 grid(B_ * H_ * (L_ / QT));   // 2*16*32 = 1024
    dim3 block(256);
    attn_fused<<<grid, block, 0, stream>>>(q, k, v, valid, scale, out_res, out_attw);
}

// Round 2
// 1119.989 us; speedup vs baseline: 1.0544x; 1.0544x over previous
//
#include <hip/hip_runtime.h>
#include <hip/hip_bf16.h>
#include <hip/hip_fp16.h>

#define L_    2048
#define D_    64
#define QT    64
#define NKT   32            // 2048 / 64
#define KGPITCH 260         // dwords per 4-row K group (256 data + 4 pad)
#define VTP   72            // u16 pitch for Vt rows (d-major)
#define PBP   72            // u16 pitch for Pbuf rows

typedef _Float16 half8 __attribute__((ext_vector_type(8)));
typedef _Float16 half2v __attribute__((ext_vector_type(2)));
typedef float    f32x4 __attribute__((ext_vector_type(4)));

__device__ __forceinline__ f32x4 mfma16f(half8 a, half8 b, f32x4 c) {
    return __builtin_amdgcn_mfma_f32_16x16x32_f16(a, b, c, 0, 0, 0);
}

__global__ __launch_bounds__(256, 4)
void attn_fused(const float* __restrict__ Qg, const float* __restrict__ Kg,
                const float* __restrict__ Vg, const int* __restrict__ validg,
                const float* __restrict__ scaleg,
                float* __restrict__ outR, float* __restrict__ outW)
{
    // K tile: fp32, 16 groups of 4 contiguous rows + 4-dword pad (global_load_lds friendly,
    // frag reads uniform 8 lanes per 4-bank window = conflict-free)
    __shared__ __attribute__((aligned(16))) float    Klds[16 * KGPITCH];   // 16640 B
    // V tile transposed [d][kk], fp16, kk-blocks XOR-swizzled so B-frags are single b128
    __shared__ __attribute__((aligned(16))) _Float16 Vt[64 * VTP];         // 9216 B
    __shared__ __attribute__((aligned(16))) _Float16 Pbuf[64 * PBP];       // 9216 B

    const int tid  = threadIdx.x;
    const int wv   = tid >> 6;
    const int lane = tid & 63;
    const int ln   = lane & 15;
    const int qd   = lane >> 4;

    // XCD-grouping swizzle: 4 bh per XCD -> K/V L2-resident per XCD
    const int bidx = blockIdx.x;
    const int bh   = (bidx & 7) * 4 + ((bidx >> 3) & 3);
    const int qt   = bidx >> 5;

    const float scale = scaleg[0];

    const float* Qb = Qg + ((size_t)bh * L_ + (size_t)qt * QT) * D_;
    const float* Kb = Kg + (size_t)bh * L_ * D_;
    const float* Vb = Vg + (size_t)bh * L_ * D_;
    const int*   Mb = validg + ((size_t)bh * L_ + (size_t)qt * QT) * (size_t)L_;
    float* Ob = outR + ((size_t)bh * L_ + (size_t)qt * QT) * D_;
    float* Wb = outW + ((size_t)bh * L_ + (size_t)qt * QT) * (size_t)L_;

    // ---- persistent Q A-fragments (fp16): A[m=ln][k=qd*8+j], frag f: d = f*32.. ----
    half8 aF[2];
    {
        const float* qrow = Qb + (size_t)(wv * 16 + ln) * D_;
#pragma unroll
        for (int f = 0; f < 2; ++f) {
            f32x4 x0 = *(const f32x4*)(qrow + f * 32 + qd * 8);
            f32x4 x1 = *(const f32x4*)(qrow + f * 32 + qd * 8 + 4);
            half8 h;
#pragma unroll
            for (int j = 0; j < 4; ++j) { h[j] = (_Float16)x0[j]; h[4 + j] = (_Float16)x1[j]; }
            aF[f] = h;
        }
    }

    // async K tile stage: 4 groups (4 rows = 1024 B) per wave, dwordx4 direct-to-LDS
    auto stageK = [&](int kt) {
        const float* gbase = Kb + (size_t)kt * 64 * 64;
#pragma unroll
        for (int gi = 0; gi < 4; ++gi) {
            const int grp = wv * 4 + gi;
            __builtin_amdgcn_global_load_lds(
                (const __attribute__((address_space(1))) void*)(gbase + grp * 256 + lane * 4),
                (__attribute__((address_space(3))) void*)&Klds[grp * KGPITCH],
                16, 0, 0);
        }
    };

    // fragment read of K row kr (fp32 in LDS -> fp16 frags), d in [0,32)+[32,64)
    auto kfrags = [&](int kr, half8& b0, half8& b1) {
        const float* kp = &Klds[(kr >> 2) * KGPITCH + (kr & 3) * 64 + qd * 8];
        f32x4 x0 = *(const f32x4*)kp;
        f32x4 x1 = *(const f32x4*)(kp + 4);
        f32x4 y0 = *(const f32x4*)(kp + 32);
        f32x4 y1 = *(const f32x4*)(kp + 36);
#pragma unroll
        for (int j = 0; j < 4; ++j) {
            b0[j] = (_Float16)x0[j]; b0[4 + j] = (_Float16)x1[j];
            b1[j] = (_Float16)y0[j]; b1[4 + j] = (_Float16)y1[j];
        }
    };

    const int* maskbase = Mb + (size_t)(wv * 16 + qd * 4) * L_ + ln;

    // ================= PHASE 1: row sums; mask -> 16 VGPRs =================
    unsigned mreg[16];
#pragma unroll
    for (int i = 0; i < 16; ++i) mreg[i] = 0u;
    float lsum[4] = {0.f, 0.f, 0.f, 0.f};

    for (int kt = 0; kt < NKT; ++kt) {
        __syncthreads();               // previous iteration's Klds readers done
        stageK(kt);
        int mv[16];
#pragma unroll
        for (int ct = 0; ct < 4; ++ct)
#pragma unroll
            for (int r = 0; r < 4; ++r)
                mv[ct * 4 + r] = maskbase[(size_t)r * L_ + kt * 64 + ct * 16];
        __syncthreads();               // K in LDS (vmcnt drain), mask regs loaded
        unsigned bits = 0;
#pragma unroll
        for (int ct = 0; ct < 4; ++ct) {
            half8 b0, b1;
            kfrags(ct * 16 + ln, b0, b1);
            f32x4 acc = {0.f, 0.f, 0.f, 0.f};
            acc = mfma16f(aF[0], b0, acc);
            acc = mfma16f(aF[1], b1, acc);
#pragma unroll
            for (int r = 0; r < 4; ++r) {
                unsigned bit = (mv[ct * 4 + r] > 0) ? 1u : 0u;
                bits |= bit << (ct * 4 + r);
                lsum[r] += (float)bit * __expf(acc[r] * scale);
            }
        }
        mreg[kt >> 1] |= bits << ((kt & 1) * 16);
    }

    float invl[4];
#pragma unroll
    for (int r = 0; r < 4; ++r) {
        float v = lsum[r];
        v += __shfl_xor(v, 1);
        v += __shfl_xor(v, 2);
        v += __shfl_xor(v, 4);
        v += __shfl_xor(v, 8);
        invl[r] = v > 0.f ? 1.f / v : 0.f;   // fully-masked row -> zeros
    }

    // ================= PHASE 2: recompute S, write att_w, accumulate O =================
    f32x4 accO[4];
#pragma unroll
    for (int i = 0; i < 4; ++i) accO[i] = (f32x4){0.f, 0.f, 0.f, 0.f};

    const int rp = tid >> 3;          // V staging: kk-pair 2rp,2rp+1
    const int vc = tid & 7;           // d-chunk
    const int dc = vc * 8;

    for (int kt = 0; kt < NKT; ++kt) {
        __syncthreads();
        stageK(kt);
        {   // stage V transposed+swizzled: Vt[d*72 + 8*((kk>>3)^((d>>3)&7)) + (kk&7)]
            const float* v0p = Vb + ((size_t)kt * 64 + 2 * rp) * 64 + dc;
            f32x4 va0 = *(const f32x4*)v0p;
            f32x4 va1 = *(const f32x4*)(v0p + 4);
            f32x4 vb0 = *(const f32x4*)(v0p + 64);
            f32x4 vb1 = *(const f32x4*)(v0p + 68);
            const int g = (rp >> 2) ^ vc;     // (d>>3)&7 == vc for d in [dc,dc+8)
#pragma unroll
            for (int i = 0; i < 8; ++i) {
                float f0 = (i < 4) ? va0[i] : va1[i - 4];
                float f1 = (i < 4) ? vb0[i] : vb1[i - 4];
                half2v h; h[0] = (_Float16)f0; h[1] = (_Float16)f1;
                const int d = dc + i;
                *(half2v*)&Vt[d * VTP + 8 * g + 2 * (rp & 3)] = h;
            }
        }
        __syncthreads();
        // QK^T + softmax -> Pbuf (own-wave rows, no barrier needed before PV)
#pragma unroll
        for (int ct = 0; ct < 4; ++ct) {
            half8 b0, b1;
            kfrags(ct * 16 + ln, b0, b1);
            f32x4 acc = {0.f, 0.f, 0.f, 0.f};
            acc = mfma16f(aF[0], b0, acc);
            acc = mfma16f(aF[1], b1, acc);
#pragma unroll
            for (int r = 0; r < 4; ++r) {
                const int qrow = wv * 16 + qd * 4 + r;
                float bit = (float)((mreg[kt >> 1] >> ((kt & 1) * 16 + ct * 4 + r)) & 1u);
                float p = bit * __expf(acc[r] * scale) * invl[r];
                Pbuf[qrow * PBP + ct * 16 + ln] = (_Float16)p;
            }
        }
        // A-frags of P (row = wv*16+ln, contiguous kk)
        half8 p0 = *(const half8*)&Pbuf[(wv * 16 + ln) * PBP + qd * 8];
        half8 p1 = *(const half8*)&Pbuf[(wv * 16 + ln) * PBP + 32 + qd * 8];
        {   // vectorized att_w store from the round-tripped fragments
            float* wp = Wb + (size_t)(wv * 16 + ln) * L_ + kt * 64;
            f32x4 s0, s1, s2, s3;
#pragma unroll
            for (int j = 0; j < 4; ++j) {
                s0[j] = (float)p0[j];     s1[j] = (float)p0[4 + j];
                s2[j] = (float)p1[j];     s3[j] = (float)p1[4 + j];
            }
            *(f32x4*)(wp + qd * 8)      = s0;
            *(f32x4*)(wp + qd * 8 + 4)  = s1;
            *(f32x4*)(wp + 32 + qd * 8)     = s2;
            *(f32x4*)(wp + 32 + qd * 8 + 4) = s3;
        }
        // PV: O += P * V  (B-frags are single b128 thanks to the swizzle)
#pragma unroll
        for (int c2 = 0; c2 < 4; ++c2) {
            const int d  = c2 * 16 + ln;
            const int g2 = (d >> 3) & 7;
            half8 v0 = *(const half8*)&Vt[d * VTP + 8 * (qd ^ g2)];
            half8 v1 = *(const half8*)&Vt[d * VTP + 8 * ((4 + qd) ^ g2)];
            accO[c2] = mfma16f(p0, v0, accO[c2]);
            accO[c2] = mfma16f(p1, v1, accO[c2]);
        }
    }

    // ---- write result ----
#pragma unroll
    for (int c2 = 0; c2 < 4; ++c2)
#pragma unroll
        for (int r = 0; r < 4; ++r)
            Ob[(size_t)(wv * 16 + qd * 4 + r) * D_ + (c2 * 16 + ln)] = accO[c2][r];
}

extern "C" void kernel_launch(void* const* d_in, const int* in_sizes, int n_in,
                              void* d_out, int out_size, void* d_ws, size_t ws_size,
                              hipStream_t stream) {
    const float* q     = (const float*)d_in[0];
    const float* k     = (const float*)d_in[1];
    const float* v     = (const float*)d_in[2];
    const int*   valid = (const int*)d_in[3];
    const float* scale = (const float*)d_in[4];

    float* out_res  = (float*)d_out;
    float* out_attw = out_res + (size_t)2 * 16 * L_ * D_;

    dim3 grid(2 * 16 * (L_ / QT));   // 1024
    dim3 block(256);
    attn_fused<<<grid, block, 0, stream>>>(q, k, v, valid, scale, out_res, out_attw);
}